// Round 3
// baseline (265.433 us; speedup 1.0000x reference)
//
#include <hip/hip_runtime.h>

#define D 1024
#define B 32
#define NI 1024
#define PP 1000
#define R 3
#define SPLITS 4        // split-K factor for weight GEMMs (K chunk = 256)
#define VS 8            // p-split factor for v_agg
#define BK 32
#define PAD 34          // row pad (floats): b64 reads land 2-way-conflict only (free)

__device__ __forceinline__ float wred(float x) {
    #pragma unroll
    for (int off = 32; off; off >>= 1) x += __shfl_xor(x, off, 64);
    return x;
}

// ---------------------------------------------------------------------------
// Tiled GEMM core: C[m, b] = sum_k A[m, k] * X[b, k]
//   BM=128 rows per block, BN=32 (all batches), BK=32, 256 threads,
//   micro-tile 4m x 4b per thread. K-range [kc0, kc0+256).
//   X rows may be a sum of NXS partial buffers (stride xss floats apart).
// ---------------------------------------------------------------------------
template<int NXS>
__device__ __forceinline__ void gemm_core(
        const float* __restrict__ A, int mbase, int Mrows,
        const float* __restrict__ Xb, int xrstride, size_t xss,
        int kc0, float acc[4][4]) {
    __shared__ float Ws[128][PAD];
    __shared__ float Xs[32][PAD];
    const int t = threadIdx.x;
    const int ty = t >> 3, tx = t & 7;   // ty 0..31, tx 0..7
    const int m0 = 4 * ty, b0 = 4 * tx;
    const int lrow = t >> 3, lq = t & 7; // staging: row 0..31, float4 idx 0..7

    #pragma unroll
    for (int i = 0; i < 4; ++i)
        #pragma unroll
        for (int j = 0; j < 4; ++j) acc[i][j] = 0.f;

    for (int kt = 0; kt < 8; ++kt) {
        const int kc = kc0 + kt * BK;
        // ---- stage W tile (128 x 32) ----
        #pragma unroll
        for (int rr = 0; rr < 4; ++rr) {
            const int row = lrow + 32 * rr;
            float4 v = make_float4(0.f, 0.f, 0.f, 0.f);
            if (mbase + row < Mrows)
                v = *(const float4*)(A + (size_t)(mbase + row) * D + kc + 4 * lq);
            *(float2*)&Ws[row][4 * lq]     = make_float2(v.x, v.y);
            *(float2*)&Ws[row][4 * lq + 2] = make_float2(v.z, v.w);
        }
        // ---- stage X tile (32 x 32), summing NXS partials ----
        {
            const float* xp = Xb + (size_t)lrow * xrstride + kc + 4 * lq;
            float4 v = *(const float4*)xp;
            #pragma unroll
            for (int s = 1; s < NXS; ++s) {
                float4 w = *(const float4*)(xp + (size_t)s * xss);
                v.x += w.x; v.y += w.y; v.z += w.z; v.w += w.w;
            }
            *(float2*)&Xs[lrow][4 * lq]     = make_float2(v.x, v.y);
            *(float2*)&Xs[lrow][4 * lq + 2] = make_float2(v.z, v.w);
        }
        __syncthreads();
        // ---- compute: 16 k-pairs ----
        #pragma unroll
        for (int kp = 0; kp < 16; ++kp) {
            float2 wv[4], xv[4];
            #pragma unroll
            for (int i = 0; i < 4; ++i) wv[i] = *(const float2*)&Ws[m0 + i][2 * kp];
            #pragma unroll
            for (int j = 0; j < 4; ++j) xv[j] = *(const float2*)&Xs[b0 + j][2 * kp];
            #pragma unroll
            for (int i = 0; i < 4; ++i)
                #pragma unroll
                for (int j = 0; j < 4; ++j) {
                    acc[i][j] += wv[i].x * xv[j].x;
                    acc[i][j] += wv[i].y * xv[j].y;
                }
        }
        __syncthreads();
    }
}

// K1: qall partials. A = W_agg (3072 x 1024), X = fc (32 x 1024).
// Cp layout: [s][b][3072]
__global__ __launch_bounds__(256) void gemm_k1(const float* __restrict__ Wagg,
        const float* __restrict__ fc, float* __restrict__ Cp) {
    const int mb = blockIdx.x, s = blockIdx.y;
    const int mbase = mb * 128;
    float acc[4][4];
    gemm_core<1>(Wagg, mbase, R * D, fc, D, 0, s * 256, acc);
    const int t = threadIdx.x, ty = t >> 3, tx = t & 7;
    const int m = mbase + 4 * ty;
    #pragma unroll
    for (int j = 0; j < 4; ++j) {
        float* cp = Cp + ((size_t)(s * B) + 4 * tx + j) * (R * D) + m;
        *(float4*)cp = make_float4(acc[0][j], acc[1][j], acc[2][j], acc[3][j]);
    }
}

// K2: score partials. A = pool (1000 x 1024), X = sum_s qall partials for row r.
// Cp layout: [s][r][b][1024] (only m<1000 valid)
__global__ __launch_bounds__(256) void gemm_k2(const float* __restrict__ pool,
        const float* __restrict__ qallp, float* __restrict__ Cp) {
    const int mb = blockIdx.x, s = blockIdx.y, r = blockIdx.z;
    const int mbase = mb * 128;
    float acc[4][4];
    gemm_core<SPLITS>(pool, mbase, PP, qallp + r * D, R * D, (size_t)B * R * D,
                      s * 256, acc);
    const int t = threadIdx.x, ty = t >> 3, tx = t & 7;
    const int m = mbase + 4 * ty;
    if (m >= PP) return;
    #pragma unroll
    for (int j = 0; j < 4; ++j) {
        float* cp = Cp + ((size_t)((s * R + r) * B) + 4 * tx + j) * D + m;
        *(float4*)cp = make_float4(acc[0][j], acc[1][j], acc[2][j], acc[3][j]);
    }
}

// K5q: q partials. A = Wq, X = fc. Writes kind 0 of qkvp.
__global__ __launch_bounds__(256) void gemm_k5q(const float* __restrict__ Wq,
        const float* __restrict__ fc, float* __restrict__ Cp) {
    const int mb = blockIdx.x, s = blockIdx.y;
    const int mbase = mb * 128;
    float acc[4][4];
    gemm_core<1>(Wq, mbase, D, fc, D, 0, s * 256, acc);
    const int t = threadIdx.x, ty = t >> 3, tx = t & 7;
    const int m = mbase + 4 * ty;
    #pragma unroll
    for (int j = 0; j < 4; ++j) {
        float* cp = Cp + ((size_t)((s * R + 0) * B) + 4 * tx + j) * D + m;
        *(float4*)cp = make_float4(acc[0][j], acc[1][j], acc[2][j], acc[3][j]);
    }
}

// K5kv: k/v partials. z: 0->Wk (kind 1), 1->Wv (kind 2). X = sum of VS vagg partials.
__global__ __launch_bounds__(256) void gemm_k5kv(const float* __restrict__ Wk,
        const float* __restrict__ Wv, const float* __restrict__ vaggp,
        float* __restrict__ Cp) {
    const int mb = blockIdx.x, s = blockIdx.y, z = blockIdx.z;
    const int mbase = mb * 128;
    const float* A = (z == 0) ? Wk : Wv;
    float acc[4][4];
    gemm_core<VS>(A, mbase, D, vaggp, D, (size_t)B * D, s * 256, acc);
    const int t = threadIdx.x, ty = t >> 3, tx = t & 7;
    const int m = mbase + 4 * ty;
    #pragma unroll
    for (int j = 0; j < 4; ++j) {
        float* cp = Cp + ((size_t)((s * R + z + 1) * B) + 4 * tx + j) * D + m;
        *(float4*)cp = make_float4(acc[0][j], acc[1][j], acc[2][j], acc[3][j]);
    }
}

// K7: v_diff pre-activation partials. A = Wc, X = u. Cp layout: [s][b][1024]
__global__ __launch_bounds__(256) void gemm_k7(const float* __restrict__ Wc,
        const float* __restrict__ u, float* __restrict__ Cp) {
    const int mb = blockIdx.x, s = blockIdx.y;
    const int mbase = mb * 128;
    float acc[4][4];
    gemm_core<1>(Wc, mbase, D, u, D, 0, s * 256, acc);
    const int t = threadIdx.x, ty = t >> 3, tx = t & 7;
    const int m = mbase + 4 * ty;
    #pragma unroll
    for (int j = 0; j < 4; ++j) {
        float* cp = Cp + ((size_t)(s * B) + 4 * tx + j) * D + m;
        *(float4*)cp = make_float4(acc[0][j], acc[1][j], acc[2][j], acc[3][j]);
    }
}

// K3: sum score partials, scale, softmax over p -> weights[(r*B+b)*PP + p]
__global__ __launch_bounds__(256) void k3_softmax(const float* __restrict__ scp,
        float* __restrict__ weights) {
    const int rb = blockIdx.x;
    const int r = rb >> 5, b = rb & 31;
    float* wrow = weights + (size_t)rb * PP;
    __shared__ float red[8];
    const int tid = threadIdx.x, w = tid >> 6, lane = tid & 63;
    float v[4];
    float mx = -1e30f;
    #pragma unroll
    for (int i = 0; i < 4; ++i) {
        const int p = tid + 256 * i;
        float x = -1e30f;
        if (p < PP) {
            x = 0.f;
            #pragma unroll
            for (int s = 0; s < SPLITS; ++s)
                x += scp[((size_t)((s * R + r) * B) + b) * D + p];
            x *= 0.03125f;
        }
        v[i] = x;
        mx = fmaxf(mx, x);
    }
    #pragma unroll
    for (int off = 32; off; off >>= 1) mx = fmaxf(mx, __shfl_xor(mx, off, 64));
    if (lane == 0) red[w] = mx;
    __syncthreads();
    mx = fmaxf(fmaxf(red[0], red[1]), fmaxf(red[2], red[3]));
    float e[4], sum = 0.f;
    #pragma unroll
    for (int i = 0; i < 4; ++i) { e[i] = __expf(v[i] - mx); sum += e[i]; }
    sum = wred(sum);
    if (lane == 0) red[4 + w] = sum;
    __syncthreads();
    const float inv = 1.f / (red[4] + red[5] + red[6] + red[7]);
    #pragma unroll
    for (int i = 0; i < 4; ++i) {
        const int p = tid + 256 * i;
        if (p < PP) wrow[p] = e[i] * inv;
    }
}

// K4: v_agg partials over p-chunks. vaggp[ps][b][d] = sum_{p in chunk} wbar[b,p]*pool[p,d]
// grid (4 d-blocks of 256 cols, VS p-splits of 125), 256 threads; acc[32] per thread.
__global__ __launch_bounds__(256) void k4_vagg(const float* __restrict__ weights,
        const float* __restrict__ pool, float* __restrict__ vaggp) {
    const int dblk = blockIdx.x, ps = blockIdx.y;
    const int d = dblk * 256 + threadIdx.x;
    __shared__ float lw[32][125];
    for (int idx = threadIdx.x; idx < 32 * 125; idx += 256) {
        const int b = idx / 125, p = idx % 125;
        const int gp = ps * 125 + p;
        lw[b][p] = (weights[(size_t)b * PP + gp] + weights[(size_t)(B + b) * PP + gp] +
                    weights[(size_t)(2 * B + b) * PP + gp]) * (1.f / 3.f);
    }
    __syncthreads();
    float acc[32];
    #pragma unroll
    for (int b = 0; b < 32; ++b) acc[b] = 0.f;
    #pragma unroll 5
    for (int p = 0; p < 125; ++p) {
        const float pv = pool[(size_t)(ps * 125 + p) * D + d];
        #pragma unroll
        for (int b = 0; b < 32; ++b) acc[b] += lw[b][p] * pv;
    }
    #pragma unroll
    for (int b = 0; b < 32; ++b)
        vaggp[((size_t)ps * B + b) * D + d] = acc[b];
}

// K6: sum qkv partials (+bias), sim = scale*dot(q,k), u = vhat - sigmoid(sim)*v
__global__ __launch_bounds__(256) void k6_u(const float* __restrict__ qkvp,
        const float* __restrict__ bq, const float* __restrict__ bk,
        const float* __restrict__ bv, const float* __restrict__ vhat,
        float* __restrict__ u) {
    const int b = blockIdx.x;
    const int t = threadIdx.x, w = t >> 6, lane = t & 63;
    const int d = 4 * t;
    float4 qv = *(const float4*)(bq + d);
    float4 kv = *(const float4*)(bk + d);
    #pragma unroll
    for (int s = 0; s < SPLITS; ++s) {
        float4 a = *(const float4*)(qkvp + ((size_t)((s * R + 0) * B) + b) * D + d);
        float4 c = *(const float4*)(qkvp + ((size_t)((s * R + 1) * B) + b) * D + d);
        qv.x += a.x; qv.y += a.y; qv.z += a.z; qv.w += a.w;
        kv.x += c.x; kv.y += c.y; kv.z += c.z; kv.w += c.w;
    }
    float local = qv.x * kv.x + qv.y * kv.y + qv.z * kv.z + qv.w * kv.w;
    local = wred(local);
    __shared__ float red[4];
    if (lane == 0) red[w] = local;
    __syncthreads();
    const float sim = (red[0] + red[1] + red[2] + red[3]) * 0.03125f;
    const float sig = 1.f / (1.f + __expf(-sim));
    float4 vv = *(const float4*)(bv + d);
    #pragma unroll
    for (int s = 0; s < SPLITS; ++s) {
        float4 c = *(const float4*)(qkvp + ((size_t)((s * R + 2) * B) + b) * D + d);
        vv.x += c.x; vv.y += c.y; vv.z += c.z; vv.w += c.w;
    }
    const float4 vh = *(const float4*)(vhat + (size_t)b * D + d);
    float4 o;
    o.x = vh.x - sig * vv.x; o.y = vh.y - sig * vv.y;
    o.z = vh.z - sig * vv.z; o.w = vh.w - sig * vv.w;
    *(float4*)(u + (size_t)b * D + d) = o;
}

// K8: vdiff[b,d] = relu(sum_s vdp + bc); cb[b] = dot(vdiff[b], Wg2) + bg
__global__ __launch_bounds__(256) void k8_cb(const float* __restrict__ vdp,
        const float* __restrict__ bc, const float* __restrict__ Wg,
        const float* __restrict__ bg, float* __restrict__ vdiff,
        float* __restrict__ cb) {
    const int b = blockIdx.x;
    const int t = threadIdx.x, w = t >> 6, lane = t & 63;
    const int d = 4 * t;
    float4 a = *(const float4*)(bc + d);
    #pragma unroll
    for (int s = 0; s < SPLITS; ++s) {
        float4 c = *(const float4*)(vdp + ((size_t)(s * B) + b) * D + d);
        a.x += c.x; a.y += c.y; a.z += c.z; a.w += c.w;
    }
    a.x = fmaxf(a.x, 0.f); a.y = fmaxf(a.y, 0.f);
    a.z = fmaxf(a.z, 0.f); a.w = fmaxf(a.w, 0.f);
    *(float4*)(vdiff + (size_t)b * D + d) = a;
    const float4 g2 = *(const float4*)(Wg + D + d);
    float local = a.x * g2.x + a.y * g2.y + a.z * g2.z + a.w * g2.w;
    local = wred(local);
    __shared__ float red[4];
    if (lane == 0) red[w] = local;
    __syncthreads();
    if (t == 0) cb[b] = red[0] + red[1] + red[2] + red[3] + bg[0];
}

// K9: out[b,n,d] = att + rs * sigmoid(att[b,n,:].Wg1 + cb[b]) * vdiff[b,d]
__global__ __launch_bounds__(256) void k9_main(const float* __restrict__ att,
        const float* __restrict__ Wg, const float* __restrict__ cb,
        const float* __restrict__ vdiff, const float* __restrict__ rs_p,
        float* __restrict__ out) {
    const int w = threadIdx.x >> 6, lane = threadIdx.x & 63;
    const size_t row = (size_t)blockIdx.x * 4 + w;
    const int b = (int)(row >> 10);
    const float* arow = att + row * D;
    float4 a[4];
    float acc = 0.f;
    #pragma unroll
    for (int kk = 0; kk < 4; ++kk) {
        const int col = 4 * lane + 256 * kk;
        a[kk] = *(const float4*)(arow + col);
        float4 g = *(const float4*)(Wg + col);
        acc += a[kk].x * g.x + a[kk].y * g.y + a[kk].z * g.z + a[kk].w * g.w;
    }
    acc = wred(acc) + cb[b];
    const float gv = 1.f / (1.f + __expf(-acc));
    const float grs = gv * rs_p[0];
    float* orow = out + row * D;
    #pragma unroll
    for (int kk = 0; kk < 4; ++kk) {
        const int col = 4 * lane + 256 * kk;
        float4 vd = *(const float4*)(vdiff + (size_t)b * D + col);
        float4 o;
        o.x = a[kk].x + grs * vd.x; o.y = a[kk].y + grs * vd.y;
        o.z = a[kk].z + grs * vd.z; o.w = a[kk].w + grs * vd.w;
        *(float4*)(orow + col) = o;
    }
}

extern "C" void kernel_launch(void* const* d_in, const int* in_sizes, int n_in,
                              void* d_out, int out_size, void* d_ws, size_t ws_size,
                              hipStream_t stream) {
    const float* att  = (const float*)d_in[0];
    const float* fc   = (const float*)d_in[1];
    const float* pool = (const float*)d_in[2];
    const float* Wagg = (const float*)d_in[3];
    const float* Wq   = (const float*)d_in[4];
    const float* bq   = (const float*)d_in[5];
    const float* Wk   = (const float*)d_in[6];
    const float* bk   = (const float*)d_in[7];
    const float* Wv   = (const float*)d_in[8];
    const float* bv   = (const float*)d_in[9];
    const float* Wc   = (const float*)d_in[10];
    const float* bc   = (const float*)d_in[11];
    const float* Wg   = (const float*)d_in[12];
    const float* bg   = (const float*)d_in[13];
    const float* rs   = (const float*)d_in[14];
    float* out = (float*)d_out;

    float* ws = (float*)d_ws;
    float* qallp   = ws;                                  // SPLITS*B*R*D = 393216
    float* scp     = qallp + (size_t)SPLITS * B * R * D;  // SPLITS*R*B*D = 393216
    float* weights = scp + (size_t)SPLITS * R * B * D;    // R*B*PP = 96000
    float* vaggp   = weights + (size_t)R * B * PP;        // VS*B*D = 262144
    float* qkvp    = vaggp + (size_t)VS * B * D;          // SPLITS*R*B*D = 393216
    float* ub      = qkvp + (size_t)SPLITS * R * B * D;   // B*D
    float* vdp     = ub + (size_t)B * D;                  // SPLITS*B*D = 131072
    float* vdiff   = vdp + (size_t)SPLITS * B * D;        // B*D
    float* cbuf    = vdiff + (size_t)B * D;               // B

    gemm_k1<<<dim3(24, SPLITS), 256, 0, stream>>>(Wagg, fc, qallp);
    gemm_k5q<<<dim3(8, SPLITS), 256, 0, stream>>>(Wq, fc, qkvp);   // independent of k1-k4
    gemm_k2<<<dim3(8, SPLITS, R), 256, 0, stream>>>(pool, qallp, scp);
    k3_softmax<<<R * B, 256, 0, stream>>>(scp, weights);
    k4_vagg<<<dim3(4, VS), 256, 0, stream>>>(weights, pool, vaggp);
    gemm_k5kv<<<dim3(8, SPLITS, 2), 256, 0, stream>>>(Wk, Wv, vaggp, qkvp);
    k6_u<<<B, 256, 0, stream>>>(qkvp, bq, bk, bv, fc, ub);
    gemm_k7<<<dim3(8, SPLITS), 256, 0, stream>>>(Wc, ub, vdp);
    k8_cb<<<B, 256, 0, stream>>>(vdp, bc, Wg, bg, vdiff, cbuf);
    k9_main<<<B * NI / 4, 256, 0, stream>>>(att, Wg, cbuf, vdiff, rs, out);
}

// Round 4
// 197.573 us; speedup vs baseline: 1.3435x; 1.3435x over previous
//
#include <hip/hip_runtime.h>

#define D 1024
#define B 32
#define NI 1024
#define PP 1000
#define R 3
#define SPLITS 4        // split-K factor for weight GEMMs (K chunk = 256)
#define VS 8            // p-split factor for v_agg (128 padded p each)
#define BK 32
#define PAD 34          // row pad (floats): b64 reads land 2-way-conflict only (free)

typedef float f32x4_t __attribute__((ext_vector_type(4)));

__device__ __forceinline__ void nt_store4(float* p, float4 v) {
    f32x4_t x = {v.x, v.y, v.z, v.w};
    __builtin_nontemporal_store(x, (f32x4_t*)p);
}

__device__ __forceinline__ float wred(float x) {
    #pragma unroll
    for (int off = 32; off; off >>= 1) x += __shfl_xor(x, off, 64);
    return x;
}
__device__ __forceinline__ float wmax(float x) {
    #pragma unroll
    for (int off = 32; off; off >>= 1) x = fmaxf(x, __shfl_xor(x, off, 64));
    return x;
}

// ---------------------------------------------------------------------------
// Tiled GEMM core: C[m, b] = sum_k A[m, k] * X[b, k]
// ---------------------------------------------------------------------------
template<int NXS>
__device__ __forceinline__ void gemm_core(
        const float* __restrict__ A, int mbase, int Mrows,
        const float* __restrict__ Xb, int xrstride, size_t xss,
        int kc0, float acc[4][4]) {
    __shared__ float Ws[128][PAD];
    __shared__ float Xs[32][PAD];
    const int t = threadIdx.x;
    const int ty = t >> 3, tx = t & 7;
    const int m0 = 4 * ty, b0 = 4 * tx;
    const int lrow = t >> 3, lq = t & 7;

    #pragma unroll
    for (int i = 0; i < 4; ++i)
        #pragma unroll
        for (int j = 0; j < 4; ++j) acc[i][j] = 0.f;

    for (int kt = 0; kt < 8; ++kt) {
        const int kc = kc0 + kt * BK;
        #pragma unroll
        for (int rr = 0; rr < 4; ++rr) {
            const int row = lrow + 32 * rr;
            float4 v = make_float4(0.f, 0.f, 0.f, 0.f);
            if (mbase + row < Mrows)
                v = *(const float4*)(A + (size_t)(mbase + row) * D + kc + 4 * lq);
            *(float2*)&Ws[row][4 * lq]     = make_float2(v.x, v.y);
            *(float2*)&Ws[row][4 * lq + 2] = make_float2(v.z, v.w);
        }
        {
            const float* xp = Xb + (size_t)lrow * xrstride + kc + 4 * lq;
            float4 v = *(const float4*)xp;
            #pragma unroll
            for (int s = 1; s < NXS; ++s) {
                float4 w = *(const float4*)(xp + (size_t)s * xss);
                v.x += w.x; v.y += w.y; v.z += w.z; v.w += w.w;
            }
            *(float2*)&Xs[lrow][4 * lq]     = make_float2(v.x, v.y);
            *(float2*)&Xs[lrow][4 * lq + 2] = make_float2(v.z, v.w);
        }
        __syncthreads();
        #pragma unroll
        for (int kp = 0; kp < 16; ++kp) {
            float2 wv[4], xv[4];
            #pragma unroll
            for (int i = 0; i < 4; ++i) wv[i] = *(const float2*)&Ws[m0 + i][2 * kp];
            #pragma unroll
            for (int j = 0; j < 4; ++j) xv[j] = *(const float2*)&Xs[b0 + j][2 * kp];
            #pragma unroll
            for (int i = 0; i < 4; ++i)
                #pragma unroll
                for (int j = 0; j < 4; ++j) {
                    acc[i][j] += wv[i].x * xv[j].x;
                    acc[i][j] += wv[i].y * xv[j].y;
                }
        }
        __syncthreads();
    }
}

// K1: qall partials. Cp layout: [s][b][3072]
__global__ __launch_bounds__(256) void gemm_k1(const float* __restrict__ Wagg,
        const float* __restrict__ fc, float* __restrict__ Cp) {
    const int mb = blockIdx.x, s = blockIdx.y;
    const int mbase = mb * 128;
    float acc[4][4];
    gemm_core<1>(Wagg, mbase, R * D, fc, D, 0, s * 256, acc);
    const int t = threadIdx.x, ty = t >> 3, tx = t & 7;
    const int m = mbase + 4 * ty;
    #pragma unroll
    for (int j = 0; j < 4; ++j) {
        float* cp = Cp + ((size_t)(s * B) + 4 * tx + j) * (R * D) + m;
        *(float4*)cp = make_float4(acc[0][j], acc[1][j], acc[2][j], acc[3][j]);
    }
}

// K2: score partials. Cp layout: [s][r][b][1024] (only m<1000 valid)
__global__ __launch_bounds__(256) void gemm_k2(const float* __restrict__ pool,
        const float* __restrict__ qallp, float* __restrict__ Cp) {
    const int mb = blockIdx.x, s = blockIdx.y, r = blockIdx.z;
    const int mbase = mb * 128;
    float acc[4][4];
    gemm_core<SPLITS>(pool, mbase, PP, qallp + r * D, R * D, (size_t)B * R * D,
                      s * 256, acc);
    const int t = threadIdx.x, ty = t >> 3, tx = t & 7;
    const int m = mbase + 4 * ty;
    if (m >= PP) return;
    #pragma unroll
    for (int j = 0; j < 4; ++j) {
        float* cp = Cp + ((size_t)((s * R + r) * B) + 4 * tx + j) * D + m;
        *(float4*)cp = make_float4(acc[0][j], acc[1][j], acc[2][j], acc[3][j]);
    }
}

// K5q: q partials (kind 0 of qkvp)
__global__ __launch_bounds__(256) void gemm_k5q(const float* __restrict__ Wq,
        const float* __restrict__ fc, float* __restrict__ Cp) {
    const int mb = blockIdx.x, s = blockIdx.y;
    const int mbase = mb * 128;
    float acc[4][4];
    gemm_core<1>(Wq, mbase, D, fc, D, 0, s * 256, acc);
    const int t = threadIdx.x, ty = t >> 3, tx = t & 7;
    const int m = mbase + 4 * ty;
    #pragma unroll
    for (int j = 0; j < 4; ++j) {
        float* cp = Cp + ((size_t)((s * R + 0) * B) + 4 * tx + j) * D + m;
        *(float4*)cp = make_float4(acc[0][j], acc[1][j], acc[2][j], acc[3][j]);
    }
}

// K5kv: k/v partials. z: 0->Wk (kind 1), 1->Wv (kind 2). X = sum of VS vagg partials.
__global__ __launch_bounds__(256) void gemm_k5kv(const float* __restrict__ Wk,
        const float* __restrict__ Wv, const float* __restrict__ vaggp,
        float* __restrict__ Cp) {
    const int mb = blockIdx.x, s = blockIdx.y, z = blockIdx.z;
    const int mbase = mb * 128;
    const float* A = (z == 0) ? Wk : Wv;
    float acc[4][4];
    gemm_core<VS>(A, mbase, D, vaggp, D, (size_t)B * D, s * 256, acc);
    const int t = threadIdx.x, ty = t >> 3, tx = t & 7;
    const int m = mbase + 4 * ty;
    #pragma unroll
    for (int j = 0; j < 4; ++j) {
        float* cp = Cp + ((size_t)((s * R + z + 1) * B) + 4 * tx + j) * D + m;
        *(float4*)cp = make_float4(acc[0][j], acc[1][j], acc[2][j], acc[3][j]);
    }
}

// K7: v_diff pre-activation partials. Cp layout: [s][b][1024]
__global__ __launch_bounds__(256) void gemm_k7(const float* __restrict__ Wc,
        const float* __restrict__ u, float* __restrict__ Cp) {
    const int mb = blockIdx.x, s = blockIdx.y;
    const int mbase = mb * 128;
    float acc[4][4];
    gemm_core<1>(Wc, mbase, D, u, D, 0, s * 256, acc);
    const int t = threadIdx.x, ty = t >> 3, tx = t & 7;
    const int m = mbase + 4 * ty;
    #pragma unroll
    for (int j = 0; j < 4; ++j) {
        float* cp = Cp + ((size_t)(s * B) + 4 * tx + j) * D + m;
        *(float4*)cp = make_float4(acc[0][j], acc[1][j], acc[2][j], acc[3][j]);
    }
}

// K3w: per b: for r=0..2 softmax over p of summed score partials; accumulate
// wbar[b][p] = (1/3) sum_r softmax_r[p], zero-padded to 1024.
__global__ __launch_bounds__(256) void k3_wbar(const float* __restrict__ scp,
        float* __restrict__ wbar) {
    const int b = blockIdx.x;
    const int t = threadIdx.x, w = t >> 6, lane = t & 63;
    __shared__ float red[8];
    float wb[4] = {0.f, 0.f, 0.f, 0.f};
    for (int r = 0; r < R; ++r) {
        float v[4];
        float mx = -1e30f;
        #pragma unroll
        for (int i = 0; i < 4; ++i) {
            const int p = t + 256 * i;
            float x = -1e30f;
            if (p < PP) {
                x = 0.f;
                #pragma unroll
                for (int s = 0; s < SPLITS; ++s)
                    x += scp[((size_t)((s * R + r) * B) + b) * D + p];
                x *= 0.03125f;
            }
            v[i] = x;
            mx = fmaxf(mx, x);
        }
        mx = wmax(mx);
        if (lane == 0) red[w] = mx;
        __syncthreads();
        mx = fmaxf(fmaxf(red[0], red[1]), fmaxf(red[2], red[3]));
        float e[4], sum = 0.f;
        #pragma unroll
        for (int i = 0; i < 4; ++i) {
            const int p = t + 256 * i;
            e[i] = (p < PP) ? __expf(v[i] - mx) : 0.f;
            sum += e[i];
        }
        sum = wred(sum);
        if (lane == 0) red[4 + w] = sum;
        __syncthreads();
        const float inv = 1.f / (red[4] + red[5] + red[6] + red[7]);
        #pragma unroll
        for (int i = 0; i < 4; ++i) wb[i] += e[i] * inv;
        __syncthreads();   // before next r reuses red[]
    }
    #pragma unroll
    for (int i = 0; i < 4; ++i) {
        const int p = t + 256 * i;
        wbar[(size_t)b * 1024 + p] = wb[i] * (1.f / 3.f);
    }
}

// K4: v_agg partials as micro-tiled GEMM over p.
// vaggp[ps][b][d] = sum_{p in ps*128..+128} wbar[b][p] * pool[p][d]
// grid (8 d-blocks of 128, VS p-splits of 128). 4d x 4b register tile.
__global__ __launch_bounds__(256) void k4_vagg(const float* __restrict__ wbar,
        const float* __restrict__ pool, float* __restrict__ vaggp) {
    const int db = blockIdx.x, ps = blockIdx.y;
    __shared__ float Ps[32][132];   // [p][d] tile (528B row: 16B-aligned, bank-safe)
    __shared__ float Wbt[32][36];   // [p][b] transposed wbar tile (144B row)
    const int t = threadIdx.x;
    const int ty = t >> 3, tx = t & 7;
    float acc[4][4];
    #pragma unroll
    for (int i = 0; i < 4; ++i)
        #pragma unroll
        for (int j = 0; j < 4; ++j) acc[i][j] = 0.f;

    for (int pt = 0; pt < 4; ++pt) {
        const int p0 = ps * 128 + pt * 32;
        {   // stage pool tile 32p x 128d (guard p >= PP)
            const int prow = t >> 5, qc = t & 31;
            #pragma unroll
            for (int rr = 0; rr < 4; ++rr) {
                const int pr = prow + 8 * rr;
                float4 v = make_float4(0.f, 0.f, 0.f, 0.f);
                if (p0 + pr < PP)
                    v = *(const float4*)(pool + (size_t)(p0 + pr) * D + db * 128 + 4 * qc);
                *(float4*)&Ps[pr][4 * qc] = v;
            }
        }
        {   // stage wbar transposed: wbar[b][p0+4q..+3] -> Wbt[p][b]
            const int bb = t >> 3, q = t & 7;
            float4 v = *(const float4*)(wbar + (size_t)bb * 1024 + p0 + 4 * q);
            Wbt[4 * q + 0][bb] = v.x; Wbt[4 * q + 1][bb] = v.y;
            Wbt[4 * q + 2][bb] = v.z; Wbt[4 * q + 3][bb] = v.w;
        }
        __syncthreads();
        #pragma unroll
        for (int pg = 0; pg < 8; ++pg) {
            #pragma unroll
            for (int pp = 0; pp < 4; ++pp) {
                const int p = 4 * pg + pp;
                float4 xv = *(const float4*)&Ps[p][4 * ty];
                float4 wv = *(const float4*)&Wbt[p][4 * tx];
                const float xs[4] = {xv.x, xv.y, xv.z, xv.w};
                const float wsv[4] = {wv.x, wv.y, wv.z, wv.w};
                #pragma unroll
                for (int i = 0; i < 4; ++i)
                    #pragma unroll
                    for (int j = 0; j < 4; ++j)
                        acc[i][j] += xs[i] * wsv[j];
            }
        }
        __syncthreads();
    }
    const int dbase = db * 128 + 4 * ty;
    #pragma unroll
    for (int j = 0; j < 4; ++j) {
        float* op = vaggp + ((size_t)ps * B + 4 * tx + j) * D + dbase;
        *(float4*)op = make_float4(acc[0][j], acc[1][j], acc[2][j], acc[3][j]);
    }
}

// K6: sum qkv partials (+bias), sim = scale*dot(q,k), u = vhat - sigmoid(sim)*v
__global__ __launch_bounds__(256) void k6_u(const float* __restrict__ qkvp,
        const float* __restrict__ bq, const float* __restrict__ bk,
        const float* __restrict__ bv, const float* __restrict__ vhat,
        float* __restrict__ u) {
    const int b = blockIdx.x;
    const int t = threadIdx.x, w = t >> 6, lane = t & 63;
    const int d = 4 * t;
    float4 qv = *(const float4*)(bq + d);
    float4 kv = *(const float4*)(bk + d);
    #pragma unroll
    for (int s = 0; s < SPLITS; ++s) {
        float4 a = *(const float4*)(qkvp + ((size_t)((s * R + 0) * B) + b) * D + d);
        float4 c = *(const float4*)(qkvp + ((size_t)((s * R + 1) * B) + b) * D + d);
        qv.x += a.x; qv.y += a.y; qv.z += a.z; qv.w += a.w;
        kv.x += c.x; kv.y += c.y; kv.z += c.z; kv.w += c.w;
    }
    float local = qv.x * kv.x + qv.y * kv.y + qv.z * kv.z + qv.w * kv.w;
    local = wred(local);
    __shared__ float red[4];
    if (lane == 0) red[w] = local;
    __syncthreads();
    const float sim = (red[0] + red[1] + red[2] + red[3]) * 0.03125f;
    const float sig = 1.f / (1.f + __expf(-sim));
    float4 vv = *(const float4*)(bv + d);
    #pragma unroll
    for (int s = 0; s < SPLITS; ++s) {
        float4 c = *(const float4*)(qkvp + ((size_t)((s * R + 2) * B) + b) * D + d);
        vv.x += c.x; vv.y += c.y; vv.z += c.z; vv.w += c.w;
    }
    const float4 vh = *(const float4*)(vhat + (size_t)b * D + d);
    float4 o;
    o.x = vh.x - sig * vv.x; o.y = vh.y - sig * vv.y;
    o.z = vh.z - sig * vv.z; o.w = vh.w - sig * vv.w;
    *(float4*)(u + (size_t)b * D + d) = o;
}

// K8: vdiff[b,d] = relu(sum_s vdp + bc); cb[b] = dot(vdiff[b], Wg2) + bg
__global__ __launch_bounds__(256) void k8_cb(const float* __restrict__ vdp,
        const float* __restrict__ bc, const float* __restrict__ Wg,
        const float* __restrict__ bg, float* __restrict__ vdiff,
        float* __restrict__ cb) {
    const int b = blockIdx.x;
    const int t = threadIdx.x, w = t >> 6, lane = t & 63;
    const int d = 4 * t;
    float4 a = *(const float4*)(bc + d);
    #pragma unroll
    for (int s = 0; s < SPLITS; ++s) {
        float4 c = *(const float4*)(vdp + ((size_t)(s * B) + b) * D + d);
        a.x += c.x; a.y += c.y; a.z += c.z; a.w += c.w;
    }
    a.x = fmaxf(a.x, 0.f); a.y = fmaxf(a.y, 0.f);
    a.z = fmaxf(a.z, 0.f); a.w = fmaxf(a.w, 0.f);
    *(float4*)(vdiff + (size_t)b * D + d) = a;
    const float4 g2 = *(const float4*)(Wg + D + d);
    float local = a.x * g2.x + a.y * g2.y + a.z * g2.z + a.w * g2.w;
    local = wred(local);
    __shared__ float red[4];
    if (lane == 0) red[w] = local;
    __syncthreads();
    if (t == 0) cb[b] = red[0] + red[1] + red[2] + red[3] + bg[0];
}

// K9: out[b,n,d] = att + rs * sigmoid(att[b,n,:].Wg1 + cb[b]) * vdiff[b,d]
// Block = 8 rows of one b. Wg1 and vdiff[b] staged in LDS; nt stores for out.
__global__ __launch_bounds__(256) void k9_main(const float* __restrict__ att,
        const float* __restrict__ Wg, const float* __restrict__ cb,
        const float* __restrict__ vdiff, const float* __restrict__ rs_p,
        float* __restrict__ out) {
    __shared__ float wgs[1024];
    __shared__ float vds[1024];
    const int t = threadIdx.x;
    const int b = blockIdx.x >> 7;          // 128 blocks per batch
    *(float4*)&wgs[4 * t] = *(const float4*)(Wg + 4 * t);
    *(float4*)&vds[4 * t] = *(const float4*)(vdiff + (size_t)b * D + 4 * t);
    __syncthreads();
    const int w = t >> 6, lane = t & 63;
    const float rsv = rs_p[0];
    const float cbb = cb[b];
    #pragma unroll
    for (int rr = 0; rr < 2; ++rr) {
        const size_t row = (size_t)blockIdx.x * 8 + w * 2 + rr;
        const float* arow = att + row * D;
        float4 a[4];
        float acc = 0.f;
        #pragma unroll
        for (int kk = 0; kk < 4; ++kk) {
            const int col = 4 * lane + 256 * kk;
            a[kk] = *(const float4*)(arow + col);
            float4 g = *(const float4*)&wgs[col];
            acc += a[kk].x * g.x + a[kk].y * g.y + a[kk].z * g.z + a[kk].w * g.w;
        }
        acc = wred(acc) + cbb;
        const float gv = 1.f / (1.f + __expf(-acc));
        const float grs = gv * rsv;
        float* orow = out + row * D;
        #pragma unroll
        for (int kk = 0; kk < 4; ++kk) {
            const int col = 4 * lane + 256 * kk;
            float4 vd = *(const float4*)&vds[col];
            float4 o;
            o.x = a[kk].x + grs * vd.x; o.y = a[kk].y + grs * vd.y;
            o.z = a[kk].z + grs * vd.z; o.w = a[kk].w + grs * vd.w;
            nt_store4(orow + col, o);
        }
    }
}

extern "C" void kernel_launch(void* const* d_in, const int* in_sizes, int n_in,
                              void* d_out, int out_size, void* d_ws, size_t ws_size,
                              hipStream_t stream) {
    const float* att  = (const float*)d_in[0];
    const float* fc   = (const float*)d_in[1];
    const float* pool = (const float*)d_in[2];
    const float* Wagg = (const float*)d_in[3];
    const float* Wq   = (const float*)d_in[4];
    const float* bq   = (const float*)d_in[5];
    const float* Wk   = (const float*)d_in[6];
    const float* bk   = (const float*)d_in[7];
    const float* Wv   = (const float*)d_in[8];
    const float* bv   = (const float*)d_in[9];
    const float* Wc   = (const float*)d_in[10];
    const float* bc   = (const float*)d_in[11];
    const float* Wg   = (const float*)d_in[12];
    const float* bg   = (const float*)d_in[13];
    const float* rs   = (const float*)d_in[14];
    float* out = (float*)d_out;

    float* ws = (float*)d_ws;
    float* qallp = ws;                                  // SPLITS*B*R*D = 393216
    float* scp   = qallp + (size_t)SPLITS * B * R * D;  // SPLITS*R*B*D = 393216
    float* wbar  = scp + (size_t)SPLITS * R * B * D;    // B*1024 = 32768
    float* vaggp = wbar + (size_t)B * 1024;             // VS*B*D = 262144
    float* qkvp  = vaggp + (size_t)VS * B * D;          // SPLITS*R*B*D = 393216
    float* ub    = qkvp + (size_t)SPLITS * R * B * D;   // B*D
    float* vdp   = ub + (size_t)B * D;                  // SPLITS*B*D = 131072
    float* vdiff = vdp + (size_t)SPLITS * B * D;        // B*D
    float* cbuf  = vdiff + (size_t)B * D;               // B

    gemm_k1<<<dim3(24, SPLITS), 256, 0, stream>>>(Wagg, fc, qallp);
    gemm_k5q<<<dim3(8, SPLITS), 256, 0, stream>>>(Wq, fc, qkvp);
    gemm_k2<<<dim3(8, SPLITS, R), 256, 0, stream>>>(pool, qallp, scp);
    k3_wbar<<<B, 256, 0, stream>>>(scp, wbar);
    k4_vagg<<<dim3(8, VS), 256, 0, stream>>>(wbar, pool, vaggp);
    gemm_k5kv<<<dim3(8, SPLITS, 2), 256, 0, stream>>>(Wk, Wv, vaggp, qkvp);
    k6_u<<<B, 256, 0, stream>>>(qkvp, bq, bk, bv, fc, ub);
    gemm_k7<<<dim3(8, SPLITS), 256, 0, stream>>>(Wc, ub, vdp);
    k8_cb<<<B, 256, 0, stream>>>(vdp, bc, Wg, bg, vdiff, cbuf);
    k9_main<<<B * NI / 8, 256, 0, stream>>>(att, Wg, cbuf, vdiff, rs, out);
}

// Round 5
// 143.343 us; speedup vs baseline: 1.8517x; 1.3783x over previous
//
#include <hip/hip_runtime.h>

#define D 1024
#define B 32
#define NI 1024
#define PP 1000
#define R 3
#define SPLITS 8        // split-K factor for weight GEMMs (K chunk = 128)
#define VS 8            // p-split factor for v_agg (128 padded p each)
#define BK 32
#define KT (D / SPLITS / BK)   // 4 k-tiles per split
#define PAD 34          // row pad (floats): b64 reads land 2-way-conflict only (free)

typedef float f32x4_t __attribute__((ext_vector_type(4)));

__device__ __forceinline__ void nt_store4(float* p, float4 v) {
    f32x4_t x = {v.x, v.y, v.z, v.w};
    __builtin_nontemporal_store(x, (f32x4_t*)p);
}

__device__ __forceinline__ float wred(float x) {
    #pragma unroll
    for (int off = 32; off; off >>= 1) x += __shfl_xor(x, off, 64);
    return x;
}
__device__ __forceinline__ float wmax(float x) {
    #pragma unroll
    for (int off = 32; off; off >>= 1) x = fmaxf(x, __shfl_xor(x, off, 64));
    return x;
}

// ---------------------------------------------------------------------------
// Tiled GEMM core: C[m, b] = sum_k A[m, k] * X[b, k], K-range [kc0, kc0+128)
// ---------------------------------------------------------------------------
template<int NXS>
__device__ __forceinline__ void gemm_core(
        const float* __restrict__ A, int mbase, int Mrows,
        const float* __restrict__ Xb, int xrstride, size_t xss,
        int kc0, float acc[4][4]) {
    __shared__ float Ws[128][PAD];
    __shared__ float Xs[32][PAD];
    const int t = threadIdx.x;
    const int ty = t >> 3, tx = t & 7;
    const int m0 = 4 * ty, b0 = 4 * tx;
    const int lrow = t >> 3, lq = t & 7;

    #pragma unroll
    for (int i = 0; i < 4; ++i)
        #pragma unroll
        for (int j = 0; j < 4; ++j) acc[i][j] = 0.f;

    for (int kt = 0; kt < KT; ++kt) {
        const int kc = kc0 + kt * BK;
        #pragma unroll
        for (int rr = 0; rr < 4; ++rr) {
            const int row = lrow + 32 * rr;
            float4 v = make_float4(0.f, 0.f, 0.f, 0.f);
            if (mbase + row < Mrows)
                v = *(const float4*)(A + (size_t)(mbase + row) * D + kc + 4 * lq);
            *(float2*)&Ws[row][4 * lq]     = make_float2(v.x, v.y);
            *(float2*)&Ws[row][4 * lq + 2] = make_float2(v.z, v.w);
        }
        {
            const float* xp = Xb + (size_t)lrow * xrstride + kc + 4 * lq;
            float4 v = *(const float4*)xp;
            #pragma unroll
            for (int s = 1; s < NXS; ++s) {
                float4 w = *(const float4*)(xp + (size_t)s * xss);
                v.x += w.x; v.y += w.y; v.z += w.z; v.w += w.w;
            }
            *(float2*)&Xs[lrow][4 * lq]     = make_float2(v.x, v.y);
            *(float2*)&Xs[lrow][4 * lq + 2] = make_float2(v.z, v.w);
        }
        __syncthreads();
        #pragma unroll
        for (int kp = 0; kp < 16; ++kp) {
            float2 wv[4], xv[4];
            #pragma unroll
            for (int i = 0; i < 4; ++i) wv[i] = *(const float2*)&Ws[m0 + i][2 * kp];
            #pragma unroll
            for (int j = 0; j < 4; ++j) xv[j] = *(const float2*)&Xs[b0 + j][2 * kp];
            #pragma unroll
            for (int i = 0; i < 4; ++i)
                #pragma unroll
                for (int j = 0; j < 4; ++j) {
                    acc[i][j] += wv[i].x * xv[j].x;
                    acc[i][j] += wv[i].y * xv[j].y;
                }
        }
        __syncthreads();
    }
}

// K1: qall partials. Cp layout: [s][b][3072]
__global__ __launch_bounds__(256) void gemm_k1(const float* __restrict__ Wagg,
        const float* __restrict__ fc, float* __restrict__ Cp) {
    const int mb = blockIdx.x, s = blockIdx.y;
    const int mbase = mb * 128;
    float acc[4][4];
    gemm_core<1>(Wagg, mbase, R * D, fc, D, 0, s * 128, acc);
    const int t = threadIdx.x, ty = t >> 3, tx = t & 7;
    const int m = mbase + 4 * ty;
    #pragma unroll
    for (int j = 0; j < 4; ++j) {
        float* cp = Cp + ((size_t)(s * B) + 4 * tx + j) * (R * D) + m;
        *(float4*)cp = make_float4(acc[0][j], acc[1][j], acc[2][j], acc[3][j]);
    }
}

// K2: score partials. Cp layout: [s][r][b][1024] (only m<1000 valid)
__global__ __launch_bounds__(256) void gemm_k2(const float* __restrict__ pool,
        const float* __restrict__ qallp, float* __restrict__ Cp) {
    const int mb = blockIdx.x, s = blockIdx.y, r = blockIdx.z;
    const int mbase = mb * 128;
    float acc[4][4];
    gemm_core<SPLITS>(pool, mbase, PP, qallp + r * D, R * D, (size_t)B * R * D,
                      s * 128, acc);
    const int t = threadIdx.x, ty = t >> 3, tx = t & 7;
    const int m = mbase + 4 * ty;
    if (m >= PP) return;
    #pragma unroll
    for (int j = 0; j < 4; ++j) {
        float* cp = Cp + ((size_t)((s * R + r) * B) + 4 * tx + j) * D + m;
        *(float4*)cp = make_float4(acc[0][j], acc[1][j], acc[2][j], acc[3][j]);
    }
}

// K5q: q partials (kind 0 of qkvp)
__global__ __launch_bounds__(256) void gemm_k5q(const float* __restrict__ Wq,
        const float* __restrict__ fc, float* __restrict__ Cp) {
    const int mb = blockIdx.x, s = blockIdx.y;
    const int mbase = mb * 128;
    float acc[4][4];
    gemm_core<1>(Wq, mbase, D, fc, D, 0, s * 128, acc);
    const int t = threadIdx.x, ty = t >> 3, tx = t & 7;
    const int m = mbase + 4 * ty;
    #pragma unroll
    for (int j = 0; j < 4; ++j) {
        float* cp = Cp + ((size_t)((s * R + 0) * B) + 4 * tx + j) * D + m;
        *(float4*)cp = make_float4(acc[0][j], acc[1][j], acc[2][j], acc[3][j]);
    }
}

// K5kv: k/v partials. z: 0->Wk (kind 1), 1->Wv (kind 2). X = sum of VS vagg partials.
__global__ __launch_bounds__(256) void gemm_k5kv(const float* __restrict__ Wk,
        const float* __restrict__ Wv, const float* __restrict__ vaggp,
        float* __restrict__ Cp) {
    const int mb = blockIdx.x, s = blockIdx.y, z = blockIdx.z;
    const int mbase = mb * 128;
    const float* A = (z == 0) ? Wk : Wv;
    float acc[4][4];
    gemm_core<VS>(A, mbase, D, vaggp, D, (size_t)B * D, s * 128, acc);
    const int t = threadIdx.x, ty = t >> 3, tx = t & 7;
    const int m = mbase + 4 * ty;
    #pragma unroll
    for (int j = 0; j < 4; ++j) {
        float* cp = Cp + ((size_t)((s * R + z + 1) * B) + 4 * tx + j) * D + m;
        *(float4*)cp = make_float4(acc[0][j], acc[1][j], acc[2][j], acc[3][j]);
    }
}

// K7: v_diff pre-activation partials. Cp layout: [s][b][1024]
__global__ __launch_bounds__(256) void gemm_k7(const float* __restrict__ Wc,
        const float* __restrict__ u, float* __restrict__ Cp) {
    const int mb = blockIdx.x, s = blockIdx.y;
    const int mbase = mb * 128;
    float acc[4][4];
    gemm_core<1>(Wc, mbase, D, u, D, 0, s * 128, acc);
    const int t = threadIdx.x, ty = t >> 3, tx = t & 7;
    const int m = mbase + 4 * ty;
    #pragma unroll
    for (int j = 0; j < 4; ++j) {
        float* cp = Cp + ((size_t)(s * B) + 4 * tx + j) * D + m;
        *(float4*)cp = make_float4(acc[0][j], acc[1][j], acc[2][j], acc[3][j]);
    }
}

// K3w: per b: for r=0..2 softmax over p of summed score partials; accumulate
// wbar[b][p] = (1/3) sum_r softmax_r[p], zero-padded to 1024.
__global__ __launch_bounds__(256) void k3_wbar(const float* __restrict__ scp,
        float* __restrict__ wbar) {
    const int b = blockIdx.x;
    const int t = threadIdx.x, w = t >> 6, lane = t & 63;
    __shared__ float red[8];
    float wb[4] = {0.f, 0.f, 0.f, 0.f};
    for (int r = 0; r < R; ++r) {
        float v[4];
        float mx = -1e30f;
        #pragma unroll
        for (int i = 0; i < 4; ++i) {
            const int p = t + 256 * i;
            float x = -1e30f;
            if (p < PP) {
                x = 0.f;
                #pragma unroll
                for (int s = 0; s < SPLITS; ++s)
                    x += scp[((size_t)((s * R + r) * B) + b) * D + p];
                x *= 0.03125f;
            }
            v[i] = x;
            mx = fmaxf(mx, x);
        }
        mx = wmax(mx);
        if (lane == 0) red[w] = mx;
        __syncthreads();
        mx = fmaxf(fmaxf(red[0], red[1]), fmaxf(red[2], red[3]));
        float e[4], sum = 0.f;
        #pragma unroll
        for (int i = 0; i < 4; ++i) {
            const int p = t + 256 * i;
            e[i] = (p < PP) ? __expf(v[i] - mx) : 0.f;
            sum += e[i];
        }
        sum = wred(sum);
        if (lane == 0) red[4 + w] = sum;
        __syncthreads();
        const float inv = 1.f / (red[4] + red[5] + red[6] + red[7]);
        #pragma unroll
        for (int i = 0; i < 4; ++i) wb[i] += e[i] * inv;
        __syncthreads();
    }
    #pragma unroll
    for (int i = 0; i < 4; ++i) {
        const int p = t + 256 * i;
        wbar[(size_t)b * 1024 + p] = wb[i] * (1.f / 3.f);
    }
}

// K4: v_agg partials as micro-tiled GEMM over p.
__global__ __launch_bounds__(256) void k4_vagg(const float* __restrict__ wbar,
        const float* __restrict__ pool, float* __restrict__ vaggp) {
    const int db = blockIdx.x, ps = blockIdx.y;
    __shared__ float Ps[32][132];
    __shared__ float Wbt[32][36];
    const int t = threadIdx.x;
    const int ty = t >> 3, tx = t & 7;
    float acc[4][4];
    #pragma unroll
    for (int i = 0; i < 4; ++i)
        #pragma unroll
        for (int j = 0; j < 4; ++j) acc[i][j] = 0.f;

    for (int pt = 0; pt < 4; ++pt) {
        const int p0 = ps * 128 + pt * 32;
        {
            const int prow = t >> 5, qc = t & 31;
            #pragma unroll
            for (int rr = 0; rr < 4; ++rr) {
                const int pr = prow + 8 * rr;
                float4 v = make_float4(0.f, 0.f, 0.f, 0.f);
                if (p0 + pr < PP)
                    v = *(const float4*)(pool + (size_t)(p0 + pr) * D + db * 128 + 4 * qc);
                *(float4*)&Ps[pr][4 * qc] = v;
            }
        }
        {
            const int bb = t >> 3, q = t & 7;
            float4 v = *(const float4*)(wbar + (size_t)bb * 1024 + p0 + 4 * q);
            Wbt[4 * q + 0][bb] = v.x; Wbt[4 * q + 1][bb] = v.y;
            Wbt[4 * q + 2][bb] = v.z; Wbt[4 * q + 3][bb] = v.w;
        }
        __syncthreads();
        #pragma unroll
        for (int pg = 0; pg < 8; ++pg) {
            #pragma unroll
            for (int pp = 0; pp < 4; ++pp) {
                const int p = 4 * pg + pp;
                float4 xv = *(const float4*)&Ps[p][4 * ty];
                float4 wv = *(const float4*)&Wbt[p][4 * tx];
                const float xs[4] = {xv.x, xv.y, xv.z, xv.w};
                const float wsv[4] = {wv.x, wv.y, wv.z, wv.w};
                #pragma unroll
                for (int i = 0; i < 4; ++i)
                    #pragma unroll
                    for (int j = 0; j < 4; ++j)
                        acc[i][j] += xs[i] * wsv[j];
            }
        }
        __syncthreads();
    }
    const int dbase = db * 128 + 4 * ty;
    #pragma unroll
    for (int j = 0; j < 4; ++j) {
        float* op = vaggp + ((size_t)ps * B + 4 * tx + j) * D + dbase;
        *(float4*)op = make_float4(acc[0][j], acc[1][j], acc[2][j], acc[3][j]);
    }
}

// K6: sum qkv partials (+bias), sim = scale*dot(q,k), u = vhat - sigmoid(sim)*v
__global__ __launch_bounds__(256) void k6_u(const float* __restrict__ qkvp,
        const float* __restrict__ bq, const float* __restrict__ bk,
        const float* __restrict__ bv, const float* __restrict__ vhat,
        float* __restrict__ u) {
    const int b = blockIdx.x;
    const int t = threadIdx.x, w = t >> 6, lane = t & 63;
    const int d = 4 * t;
    float4 qv = *(const float4*)(bq + d);
    float4 kv = *(const float4*)(bk + d);
    #pragma unroll
    for (int s = 0; s < SPLITS; ++s) {
        float4 a = *(const float4*)(qkvp + ((size_t)((s * R + 0) * B) + b) * D + d);
        float4 c = *(const float4*)(qkvp + ((size_t)((s * R + 1) * B) + b) * D + d);
        qv.x += a.x; qv.y += a.y; qv.z += a.z; qv.w += a.w;
        kv.x += c.x; kv.y += c.y; kv.z += c.z; kv.w += c.w;
    }
    float local = qv.x * kv.x + qv.y * kv.y + qv.z * kv.z + qv.w * kv.w;
    local = wred(local);
    __shared__ float red[4];
    if (lane == 0) red[w] = local;
    __syncthreads();
    const float sim = (red[0] + red[1] + red[2] + red[3]) * 0.03125f;
    const float sig = 1.f / (1.f + __expf(-sim));
    float4 vv = *(const float4*)(bv + d);
    #pragma unroll
    for (int s = 0; s < SPLITS; ++s) {
        float4 c = *(const float4*)(qkvp + ((size_t)((s * R + 2) * B) + b) * D + d);
        vv.x += c.x; vv.y += c.y; vv.z += c.z; vv.w += c.w;
    }
    const float4 vh = *(const float4*)(vhat + (size_t)b * D + d);
    float4 o;
    o.x = vh.x - sig * vv.x; o.y = vh.y - sig * vv.y;
    o.z = vh.z - sig * vv.z; o.w = vh.w - sig * vv.w;
    *(float4*)(u + (size_t)b * D + d) = o;
}

// K8: vdiff[b,d] = relu(sum_s vdp + bc); cb[b] = dot(vdiff[b], Wg2) + bg
__global__ __launch_bounds__(256) void k8_cb(const float* __restrict__ vdp,
        const float* __restrict__ bc, const float* __restrict__ Wg,
        const float* __restrict__ bg, float* __restrict__ vdiff,
        float* __restrict__ cb) {
    const int b = blockIdx.x;
    const int t = threadIdx.x, w = t >> 6, lane = t & 63;
    const int d = 4 * t;
    float4 a = *(const float4*)(bc + d);
    #pragma unroll
    for (int s = 0; s < SPLITS; ++s) {
        float4 c = *(const float4*)(vdp + ((size_t)(s * B) + b) * D + d);
        a.x += c.x; a.y += c.y; a.z += c.z; a.w += c.w;
    }
    a.x = fmaxf(a.x, 0.f); a.y = fmaxf(a.y, 0.f);
    a.z = fmaxf(a.z, 0.f); a.w = fmaxf(a.w, 0.f);
    *(float4*)(vdiff + (size_t)b * D + d) = a;
    const float4 g2 = *(const float4*)(Wg + D + d);
    float local = a.x * g2.x + a.y * g2.y + a.z * g2.z + a.w * g2.w;
    local = wred(local);
    __shared__ float red[4];
    if (lane == 0) red[w] = local;
    __syncthreads();
    if (t == 0) cb[b] = red[0] + red[1] + red[2] + red[3] + bg[0];
}

// K9: out[b,n,d] = att + rs * sigmoid(att[b,n,:].Wg1 + cb[b]) * vdiff[b,d]
// 4 rows per wave (16 outstanding loads), interleaved butterfly reductions.
__global__ __launch_bounds__(256) void k9_main(const float* __restrict__ att,
        const float* __restrict__ Wg, const float* __restrict__ cb,
        const float* __restrict__ vdiff, const float* __restrict__ rs_p,
        float* __restrict__ out) {
    __shared__ float wgs[1024];
    __shared__ float vds[1024];
    const int t = threadIdx.x;
    const int b = blockIdx.x >> 6;          // 64 blocks per batch (16 rows each)
    *(float4*)&wgs[4 * t] = *(const float4*)(Wg + 4 * t);
    *(float4*)&vds[4 * t] = *(const float4*)(vdiff + (size_t)b * D + 4 * t);
    __syncthreads();
    const int w = t >> 6, lane = t & 63;
    const float rsv = rs_p[0];
    const float cbb = cb[b];
    const size_t row0 = (size_t)blockIdx.x * 16 + w * 4;

    float4 a[4][4];
    #pragma unroll
    for (int rr = 0; rr < 4; ++rr) {
        const float* arow = att + (row0 + rr) * D;
        #pragma unroll
        for (int kk = 0; kk < 4; ++kk)
            a[rr][kk] = *(const float4*)(arow + 4 * lane + 256 * kk);
    }
    float acc[4];
    #pragma unroll
    for (int rr = 0; rr < 4; ++rr) {
        float s = 0.f;
        #pragma unroll
        for (int kk = 0; kk < 4; ++kk) {
            const int col = 4 * lane + 256 * kk;
            float4 g = *(const float4*)&wgs[col];
            s += a[rr][kk].x * g.x + a[rr][kk].y * g.y +
                 a[rr][kk].z * g.z + a[rr][kk].w * g.w;
        }
        acc[rr] = s;
    }
    #pragma unroll
    for (int off = 32; off; off >>= 1) {
        #pragma unroll
        for (int rr = 0; rr < 4; ++rr) acc[rr] += __shfl_xor(acc[rr], off, 64);
    }
    #pragma unroll
    for (int rr = 0; rr < 4; ++rr) {
        const float gv = 1.f / (1.f + __expf(-(acc[rr] + cbb)));
        const float grs = gv * rsv;
        float* orow = out + (row0 + rr) * D;
        #pragma unroll
        for (int kk = 0; kk < 4; ++kk) {
            const int col = 4 * lane + 256 * kk;
            float4 vd = *(const float4*)&vds[col];
            float4 o;
            o.x = a[rr][kk].x + grs * vd.x; o.y = a[rr][kk].y + grs * vd.y;
            o.z = a[rr][kk].z + grs * vd.z; o.w = a[rr][kk].w + grs * vd.w;
            nt_store4(orow + col, o);
        }
    }
}

extern "C" void kernel_launch(void* const* d_in, const int* in_sizes, int n_in,
                              void* d_out, int out_size, void* d_ws, size_t ws_size,
                              hipStream_t stream) {
    const float* att  = (const float*)d_in[0];
    const float* fc   = (const float*)d_in[1];
    const float* pool = (const float*)d_in[2];
    const float* Wagg = (const float*)d_in[3];
    const float* Wq   = (const float*)d_in[4];
    const float* bq   = (const float*)d_in[5];
    const float* Wk   = (const float*)d_in[6];
    const float* bk   = (const float*)d_in[7];
    const float* Wv   = (const float*)d_in[8];
    const float* bv   = (const float*)d_in[9];
    const float* Wc   = (const float*)d_in[10];
    const float* bc   = (const float*)d_in[11];
    const float* Wg   = (const float*)d_in[12];
    const float* bg   = (const float*)d_in[13];
    const float* rs   = (const float*)d_in[14];
    float* out = (float*)d_out;

    float* ws = (float*)d_ws;
    float* qallp = ws;                                  // SPLITS*B*R*D
    float* scp   = qallp + (size_t)SPLITS * B * R * D;  // SPLITS*R*B*D
    float* wbar  = scp + (size_t)SPLITS * R * B * D;    // B*1024
    float* vaggp = wbar + (size_t)B * 1024;             // VS*B*D
    float* qkvp  = vaggp + (size_t)VS * B * D;          // SPLITS*R*B*D
    float* ub    = qkvp + (size_t)SPLITS * R * B * D;   // B*D
    float* vdp   = ub + (size_t)B * D;                  // SPLITS*B*D
    float* vdiff = vdp + (size_t)SPLITS * B * D;        // B*D
    float* cbuf  = vdiff + (size_t)B * D;               // B

    gemm_k1<<<dim3(24, SPLITS), 256, 0, stream>>>(Wagg, fc, qallp);
    gemm_k5q<<<dim3(8, SPLITS), 256, 0, stream>>>(Wq, fc, qkvp);
    gemm_k2<<<dim3(8, SPLITS, R), 256, 0, stream>>>(pool, qallp, scp);
    k3_wbar<<<B, 256, 0, stream>>>(scp, wbar);
    k4_vagg<<<dim3(8, VS), 256, 0, stream>>>(wbar, pool, vaggp);
    gemm_k5kv<<<dim3(8, SPLITS, 2), 256, 0, stream>>>(Wk, Wv, vaggp, qkvp);
    k6_u<<<B, 256, 0, stream>>>(qkvp, bq, bk, bv, fc, ub);
    gemm_k7<<<dim3(8, SPLITS), 256, 0, stream>>>(Wc, ub, vdp);
    k8_cb<<<B, 256, 0, stream>>>(vdp, bc, Wg, bg, vdiff, cbuf);
    k9_main<<<B * NI / 16, 256, 0, stream>>>(att, Wg, cbuf, vdiff, rs, out);
}